// Round 8
// baseline (129.616 us; speedup 1.0000x reference)
//
#include <hip/hip_runtime.h>

// MoE dense: N=16384, D=256, E=8, H=128 (gate hidden), expert hidden 256.
// R15: TLP 2x. R14b's k_moe (48us) decomposes as MFMA 13.4 + VALU 12.7 +
// VMEM ~15 all nearly SERIAL: 512-thr blocks at 1 block/CU = 2 waves/SIMD
// can't hide ds_read/L2 latency (46% stall). This round: 1024-thr blocks
// (16 waves = 4 waves/SIMD), same grid 256 / 64-row tiles / weight traffic.
// Per-wave work halves (16 h / 16 d per wave): hacc,oacc 16 VGPR each,
// wra/wrb 8-frag double buffer 64 -> ~128 total, enforced by
// __launch_bounds__(1024,4). Gate on waves 0-7 (verbatim numerics).
// Expert loop schedule, swizzles, f2bf, accumulation order: identical to
// R14b -> absmax unchanged.
// Workspace (compacted):
//   w1f  fragment-major W1 @ 0         (1MB)
//   wg1f fragment-major Wg1 @ 1048576  (64KB)
//   w2f  fragment-major W2 @ 1114112   (1MB)

typedef unsigned short USH;
typedef float f32x4 __attribute__((ext_vector_type(4)));
typedef __bf16 bf16x8 __attribute__((ext_vector_type(8)));

__device__ __forceinline__ USH f2bf(float f) {
  unsigned int u = __float_as_uint(f);
  u += 0x7fffu + ((u >> 16) & 1u);   // RNE
  return (USH)(u >> 16);
}

// ---------------- prep (weights only) ----------------
// w1f fragment layout: value W1[e][c][h]; t=h>>4, kt=c>>6, ch=(c>>5)&1,
//   q=(c>>3)&3, u=c&7:  idx = ((e*64+kt*16+t)*2+ch)*512 + (q*16+(h&15))*8 + u
// w2f same with (h->k-role, d->out-role): value W2[e][h][d].
// wg1f: value Wg1[c][h], h in [0,128): idx = ((kt*8+t)*2+ch)*512 + ...

__global__ __launch_bounds__(256) void k_prep(
    const float* __restrict__ Wg1,
    const float* __restrict__ W1,
    const float* __restrict__ W2,
    USH* __restrict__ w1f, USH* __restrict__ w2f, USH* __restrict__ wg1f) {
  __shared__ float T[64][65];
  int b = blockIdx.x, tid = threadIdx.x;

  if (b < 128) {                // w1f
    int e = b >> 4, tl = b & 15;
    int c0 = (tl >> 2) * 64, h0 = (tl & 3) * 64;
    const float* src = W1 + (size_t)e * 65536;
#pragma unroll
    for (int p = 0; p < 4; ++p) {
      int r = p * 16 + (tid >> 4), d4 = (tid & 15) * 4;
      float4 v = *(const float4*)(src + (size_t)(c0 + r) * 256 + h0 + d4);
      T[r][d4] = v.x; T[r][d4 + 1] = v.y; T[r][d4 + 2] = v.z; T[r][d4 + 3] = v.w;
    }
    __syncthreads();
#pragma unroll
    for (int p = 0; p < 4; ++p) {
      int hr = p * 16 + (tid >> 4), c4 = (tid & 15) * 4;
      USH w[4];
#pragma unroll
      for (int j = 0; j < 4; ++j) w[j] = f2bf(T[c4 + j][hr]);   // W1[e][c0+c4+j][h0+hr]
      int h = h0 + hr;
      int t = h >> 4, lh = h & 15;
      int kt = c0 >> 6, ch = (c4 >> 5) & 1, q = (c4 >> 3) & 3, u0 = c4 & 7;
      size_t idx = ((size_t)((e * 64 + kt * 16 + t) * 2 + ch)) * 512 + (q * 16 + lh) * 8 + u0;
      *(uint2*)(w1f + idx) = *(const uint2*)w;
    }
  } else if (b < 256) {         // w2f
    int bp = b - 128;
    int e = bp >> 4, tl = bp & 15;
    int h0 = (tl >> 2) * 64, d0 = (tl & 3) * 64;
    const float* src = W2 + (size_t)e * 65536;
#pragma unroll
    for (int p = 0; p < 4; ++p) {
      int r = p * 16 + (tid >> 4), d4 = (tid & 15) * 4;
      float4 v = *(const float4*)(src + (size_t)(h0 + r) * 256 + d0 + d4);
      T[r][d4] = v.x; T[r][d4 + 1] = v.y; T[r][d4 + 2] = v.z; T[r][d4 + 3] = v.w;
    }
    __syncthreads();
#pragma unroll
    for (int p = 0; p < 4; ++p) {
      int dr = p * 16 + (tid >> 4), h4 = (tid & 15) * 4;
      USH w[4];
#pragma unroll
      for (int j = 0; j < 4; ++j) w[j] = f2bf(T[h4 + j][dr]);   // W2[e][h0+h4+j][d0+dr]
      int d = d0 + dr;
      int t = d >> 4, ld = d & 15;
      int ht = h0 >> 6, ch = (h4 >> 5) & 1, q = (h4 >> 3) & 3, u0 = h4 & 7;
      size_t idx = ((size_t)((e * 64 + ht * 16 + t) * 2 + ch)) * 512 + (q * 16 + ld) * 8 + u0;
      *(uint2*)(w2f + idx) = *(const uint2*)w;
    }
  } else {                      // wg1f (8 blocks)
    int bp = b - 256;
    int c0 = (bp >> 1) * 64, h0 = (bp & 1) * 64;
#pragma unroll
    for (int p = 0; p < 4; ++p) {
      int r = p * 16 + (tid >> 4), d4 = (tid & 15) * 4;
      float4 v = *(const float4*)(Wg1 + (size_t)(c0 + r) * 128 + h0 + d4);
      T[r][d4] = v.x; T[r][d4 + 1] = v.y; T[r][d4 + 2] = v.z; T[r][d4 + 3] = v.w;
    }
    __syncthreads();
#pragma unroll
    for (int p = 0; p < 4; ++p) {
      int hr = p * 16 + (tid >> 4), c4 = (tid & 15) * 4;
      USH w[4];
#pragma unroll
      for (int j = 0; j < 4; ++j) w[j] = f2bf(T[c4 + j][hr]);   // Wg1[c0+c4+j][h0+hr]
      int h = h0 + hr;
      int t = h >> 4, lh = h & 15;
      int kt = c0 >> 6, ch = (c4 >> 5) & 1, q = (c4 >> 3) & 3, u0 = c4 & 7;
      size_t idx = ((size_t)((kt * 8 + t) * 2 + ch)) * 512 + (q * 16 + lh) * 8 + u0;
      *(uint2*)(wg1f + idx) = *(const uint2*)w;
    }
  }
}

// -------- fused gate + experts (256 blocks x 64 rows, 1024 thr / 16 waves) --

__global__ __launch_bounds__(1024, 4) void k_moe(
    const float* __restrict__ x,
    const USH* __restrict__ w1f,
    const USH* __restrict__ w2f,
    const USH* __restrict__ wg1f,
    const float* __restrict__ wg2,
    const float* __restrict__ bg1,
    const float* __restrict__ bg2,
    const float* __restrict__ b1,
    const float* __restrict__ b2,
    float* __restrict__ out) {
  __shared__ __align__(16) USH xs[4 * 64 * 64];   // 32KB, swizzled x tile
  __shared__ __align__(16) USH Hs[2][64 * 256];   // 64KB dbuf; Hs[0] doubles as hgs
  __shared__ float b1s[2048];
  __shared__ float b2s[2048];
  __shared__ float gse[512];                      // gse[e*64+n]
  __shared__ float wg2t[8 * 132];                 // wg2t[e][k], padded
  __shared__ float lgg[512];
  __shared__ float bg1s[128];
  __shared__ float bg2g[8];

  int tid = threadIdx.x;
  int wave = tid >> 6, lane = tid & 63;
  int quad = lane >> 4, l16 = lane & 15;
  int sw = l16 & 7;
  int rowBase = blockIdx.x * 64;
  float* hgs = (float*)&Hs[0][0];                 // 64x128 f32, slot-swizzled

  // ---- prologue: x f32 -> bf16 -> xs (swizzled); gate/bias constants
#pragma unroll
  for (int it = 0; it < 2; ++it) {
    int i = it * 1024 + tid;
    int kt = i >> 9, rem = i & 511;
    int r = rem >> 3, slot = rem & 7;
    int c8 = slot ^ (r & 7);
    const float* sp = x + (size_t)(rowBase + r) * 256 + kt * 64 + c8 * 8;
    float4 a = *(const float4*)sp;
    float4 bq = *(const float4*)(sp + 4);
    USH v[8];
    v[0] = f2bf(a.x);  v[1] = f2bf(a.y);  v[2] = f2bf(a.z);  v[3] = f2bf(a.w);
    v[4] = f2bf(bq.x); v[5] = f2bf(bq.y); v[6] = f2bf(bq.z); v[7] = f2bf(bq.w);
    *(uint4*)(xs + (size_t)i * 8) = *(const uint4*)v;
  }
#pragma unroll
  for (int t = 0; t < 2; ++t) {
    b1s[t * 1024 + tid] = b1[t * 1024 + tid];
    b2s[t * 1024 + tid] = b2[t * 1024 + tid];
  }
  if (tid < 1024) wg2t[(tid & 7) * 132 + (tid >> 3)] = wg2[tid];
  if (tid < 128) bg1s[tid] = bg1[tid];
  if (tid < 8) bg2g[tid] = bg2[tid];

  // weight fragment double buffer: 8 frags each (wave owns one 16-slice)
  bf16x8 wra[8], wrb[8];
  auto LDWH = [&](bf16x8* dst, const USH* We) {
#pragma unroll
    for (int kt = 0; kt < 4; ++kt)
#pragma unroll
      for (int c = 0; c < 2; ++c)
        dst[kt * 2 + c] = *(const bf16x8*)(
            We + (size_t)((kt * 16 + wave) * 2 + c) * 512 + lane * 8);
  };
  LDWH(wra, w1f);   // expert 0 W1, in flight across the gate

  asm volatile("s_waitcnt lgkmcnt(0)" ::: "memory");
  __builtin_amdgcn_s_barrier();

  // ---- gate stage 1 (waves 0-7): hg^T[h,n] = sum_c Wg1[c,h]*x[n,c]
  if (tid < 512) {
    f32x4 hg4[4] = {};
#pragma unroll
    for (int kt = 0; kt < 4; ++kt)
#pragma unroll
      for (int c = 0; c < 2; ++c) {
        int cs = ((c * 4 + quad) ^ sw) * 8;
        bf16x8 av = *(const bf16x8*)(wg1f + (size_t)((kt * 8 + wave) * 2 + c) * 512 + lane * 8);
        bf16x8 bv[4];
#pragma unroll
        for (int j = 0; j < 4; ++j)
          bv[j] = *(const bf16x8*)(xs + kt * 4096 + (j * 16 + l16) * 64 + cs);
#pragma unroll
        for (int j = 0; j < 4; ++j)
          hg4[j] = __builtin_amdgcn_mfma_f32_16x16x32_bf16(av, bv[j], hg4[j], 0, 0, 0);
      }
    // hgs[n][h] = relu(hg + bg1), h-slot XOR-swizzled (slot = (h>>2)^(n&7))
    int hb = wave * 16 + quad * 4;
    int slotbase = wave * 4 + quad;
#pragma unroll
    for (int j = 0; j < 4; ++j) {
      int n = j * 16 + l16;
      int slot = slotbase ^ (n & 7);
      f32x4 v;
#pragma unroll
      for (int r = 0; r < 4; ++r) v[r] = fmaxf(hg4[j][r] + bg1s[hb + r], 0.0f);
      *(f32x4*)(hgs + n * 128 + slot * 4) = v;
    }
  }
  asm volatile("s_waitcnt lgkmcnt(0)" ::: "memory");
  __builtin_amdgcn_s_barrier();

  // ---- gate stage 2: logits[n][e] (f32, same k-order as before)
  if (tid < 512) {
    int n = tid >> 3, eg = tid & 7;
    float s = bg2g[eg];
#pragma unroll
    for (int k4 = 0; k4 < 32; ++k4) {
      int slot = k4 ^ (n & 7);
      f32x4 hv = *(const f32x4*)(hgs + n * 128 + slot * 4);
      const float* wv = wg2t + eg * 132 + k4 * 4;
      s += hv[0] * wv[0]; s += hv[1] * wv[1]; s += hv[2] * wv[2]; s += hv[3] * wv[3];
    }
    lgg[tid] = s;
  }
  asm volatile("s_waitcnt lgkmcnt(0)" ::: "memory");
  __builtin_amdgcn_s_barrier();

  if (tid < 64) {               // softmax over 8 experts
    float l[8]; float m = -1e30f;
#pragma unroll
    for (int e = 0; e < 8; ++e) { l[e] = lgg[tid * 8 + e]; m = fmaxf(m, l[e]); }
    float s = 0.0f;
#pragma unroll
    for (int e = 0; e < 8; ++e) { l[e] = expf(l[e] - m); s += l[e]; }
    float inv = 1.0f / s;
#pragma unroll
    for (int e = 0; e < 8; ++e) gse[e * 64 + tid] = l[e] * inv;
  }
  asm volatile("s_waitcnt lgkmcnt(0)" ::: "memory");
  __builtin_amdgcn_s_barrier();   // gse visible; hgs (Hs[0]) now dead

  // ---- expert loop: per wave, 16 h (phase 1) / 16 d (phase 2) ----
  f32x4 oacc[4] = {};

#pragma unroll 1
  for (int e = 0; e < 8; ++e) {
    const USH* W2e = w2f + (size_t)e * 65536;
    const USH* W1n = w1f + (size_t)((e + 1) & 7) * 65536;
    f32x4 hacc[4] = {};

    // phase 1: H^T[h,n] = sum_c W1[c,h]*x[n,c]; wave owns h = wave*16..+15.
#pragma unroll
    for (int kt = 0; kt < 2; ++kt)
#pragma unroll
      for (int c = 0; c < 2; ++c) {
        int cs = ((c * 4 + quad) ^ sw) * 8;
        bf16x8 bv[4];
#pragma unroll
        for (int j = 0; j < 4; ++j)
          bv[j] = *(const bf16x8*)(xs + kt * 4096 + (j * 16 + l16) * 64 + cs);
#pragma unroll
        for (int j = 0; j < 4; ++j)
          hacc[j] = __builtin_amdgcn_mfma_f32_16x16x32_bf16(
              wra[kt * 2 + c], bv[j], hacc[j], 0, 0, 0);
      }
    LDWH(wrb, W2e);               // W2(e) frags; first use after barrier
#pragma unroll
    for (int kt = 2; kt < 4; ++kt)
#pragma unroll
      for (int c = 0; c < 2; ++c) {
        int cs = ((c * 4 + quad) ^ sw) * 8;
        bf16x8 bv[4];
#pragma unroll
        for (int j = 0; j < 4; ++j)
          bv[j] = *(const bf16x8*)(xs + kt * 4096 + (j * 16 + l16) * 64 + cs);
#pragma unroll
        for (int j = 0; j < 4; ++j)
          hacc[j] = __builtin_amdgcn_mfma_f32_16x16x32_bf16(
              wra[kt * 2 + c], bv[j], hacc[j], 0, 0, 0);
      }

    // epilogue 1: Hs[e&1][n][h] = bf16(relu(hacc+b1)*g[n,e])
    USH* Hb = &Hs[e & 1][0];
    {
      int slot = (wave & 3) * 2 + (quad >> 1);   // (h>>3)&7
      int hb = wave * 16 + quad * 4;
#pragma unroll
      for (int j = 0; j < 4; ++j) {
        int n = j * 16 + l16;
        float gg = gse[e * 64 + n];
        USH w4[4];
#pragma unroll
        for (int r = 0; r < 4; ++r)
          w4[r] = f2bf(fmaxf(hacc[j][r] + b1s[e * 256 + hb + r], 0.0f) * gg);
        int off = n * 256 + (wave >> 2) * 64 + ((slot ^ (n & 7)) * 8) + (quad & 1) * 4;
        *(uint2*)(Hb + off) = *(const uint2*)w4;
      }
    }

    // single barrier per expert: LDS drain only; weight prefetches stay live.
    asm volatile("s_waitcnt lgkmcnt(0)" ::: "memory");
    __builtin_amdgcn_s_barrier();

    // phase 2: out[n,d] += sum_h Hs[n,h]*W2[h,d]; wave owns d = wave*16..+15.
#pragma unroll
    for (int ht = 0; ht < 2; ++ht)
#pragma unroll
      for (int c = 0; c < 2; ++c) {
        int cs = ((c * 4 + quad) ^ sw) * 8;
        bf16x8 av[4];
#pragma unroll
        for (int i = 0; i < 4; ++i)
          av[i] = *(const bf16x8*)(Hb + (i * 16 + l16) * 256 + ht * 64 + cs);
#pragma unroll
        for (int i = 0; i < 4; ++i)
          oacc[i] = __builtin_amdgcn_mfma_f32_16x16x32_bf16(
              av[i], wrb[ht * 2 + c], oacc[i], 0, 0, 0);
      }
    LDWH(wra, W1n);               // next expert's W1 (e=7: dummy reload of e0)
#pragma unroll
    for (int ht = 2; ht < 4; ++ht)
#pragma unroll
      for (int c = 0; c < 2; ++c) {
        int cs = ((c * 4 + quad) ^ sw) * 8;
        bf16x8 av[4];
#pragma unroll
        for (int i = 0; i < 4; ++i)
          av[i] = *(const bf16x8*)(Hb + (i * 16 + l16) * 256 + ht * 64 + cs);
#pragma unroll
        for (int i = 0; i < 4; ++i)
          oacc[i] = __builtin_amdgcn_mfma_f32_16x16x32_bf16(
              av[i], wrb[ht * 2 + c], oacc[i], 0, 0, 0);
      }
  }

  // final epilogue: out = oacc + sum_e g[n,e]*b2[e,d]  (exact f32 bias)
#pragma unroll
  for (int i = 0; i < 4; ++i)
#pragma unroll
    for (int r = 0; r < 4; ++r) {
      int n = i * 16 + quad * 4 + r;
      size_t grow = (size_t)(rowBase + n) * 256;
      int d = wave * 16 + l16;
      float bias = 0.0f;
#pragma unroll
      for (int ee = 0; ee < 8; ++ee) bias += gse[ee * 64 + n] * b2s[ee * 256 + d];
      out[grow + d] = oacc[i][r] + bias;
    }
}

// ---------------- launch ----------------

extern "C" void kernel_launch(void* const* d_in, const int* in_sizes, int n_in,
                              void* d_out, int out_size, void* d_ws, size_t ws_size,
                              hipStream_t stream) {
  const float* x   = (const float*)d_in[0];
  const float* Wg1 = (const float*)d_in[1];
  const float* bg1 = (const float*)d_in[2];
  const float* Wg2 = (const float*)d_in[3];
  const float* bg2 = (const float*)d_in[4];
  const float* W1  = (const float*)d_in[5];
  const float* b1  = (const float*)d_in[6];
  const float* W2  = (const float*)d_in[7];
  const float* b2  = (const float*)d_in[8];
  float* out = (float*)d_out;

  char* ws = (char*)d_ws;
  USH* w1f  = (USH*)(ws);
  USH* wg1f = (USH*)(ws + 1048576);
  USH* w2f  = (USH*)(ws + 1114112);

  hipLaunchKernelGGL(k_prep, dim3(264), dim3(256), 0, stream,
                     Wg1, W1, W2, w1f, w2f, wg1f);
  hipLaunchKernelGGL(k_moe, dim3(256), dim3(1024), 0, stream,
                     x, w1f, w2f, wg1f, Wg2, bg1, bg2, b1, b2, out);
}

// Round 9
// 120.866 us; speedup vs baseline: 1.0724x; 1.0724x over previous
//
#include <hip/hip_runtime.h>

// MoE dense: N=16384, D=256, E=8, H=128 (gate hidden), expert hidden 256.
// R16: R14b + x fragments (kt 0..2) register-resident. R15's 1024-thr attempt
// failed via VGPR starvation (compiler chose 64 regs -> weight dbuf dissolved
// into rematerialized loads; LDS/CU doubled at 2 blocks/CU). R14b's 48us is
// LDS-port dominated: 4.5MB/CU (x re-read 8x = 2MB, Hs read 2MB, Hs write
// 0.5MB) @ 85B/cyc ~ 22us. This round: 24 bf16x8 xr regs (96 VGPR) hold x for
// kt=0..2, loaded ONCE from xs; phase-1 LDS reads only for kt=3. Demand ~210
// VGPR, allowed by __launch_bounds__(512,2) (cap 256). Everything else is
// R14b verbatim -> clean attribution, absmax identical.
// Workspace:
//   w1f  fragment-major W1 @ 8388608   (1MB)
//   wg1f fragment-major Wg1 @ 9437184  (64KB)
//   w2f  fragment-major W2 @ 9502720   (1MB)

typedef unsigned short USH;
typedef float f32x4 __attribute__((ext_vector_type(4)));
typedef __bf16 bf16x8 __attribute__((ext_vector_type(8)));

__device__ __forceinline__ USH f2bf(float f) {
  unsigned int u = __float_as_uint(f);
  u += 0x7fffu + ((u >> 16) & 1u);   // RNE
  return (USH)(u >> 16);
}

// ---------------- prep (weights only) ----------------
// w1f fragment layout: value W1[e][c][h]; t=h>>4, kt=c>>6, ch=(c>>5)&1,
//   q=(c>>3)&3, u=c&7:  idx = ((e*64+kt*16+t)*2+ch)*512 + (q*16+(h&15))*8 + u
// w2f same with (h->k-role, d->out-role): value W2[e][h][d].
// wg1f: value Wg1[c][h], h in [0,128): idx = ((kt*8+t)*2+ch)*512 + ...

__global__ __launch_bounds__(256) void k_prep(
    const float* __restrict__ Wg1,
    const float* __restrict__ W1,
    const float* __restrict__ W2,
    USH* __restrict__ w1f, USH* __restrict__ w2f, USH* __restrict__ wg1f) {
  __shared__ float T[64][65];
  int b = blockIdx.x, tid = threadIdx.x;

  if (b < 128) {                // w1f
    int e = b >> 4, tl = b & 15;
    int c0 = (tl >> 2) * 64, h0 = (tl & 3) * 64;
    const float* src = W1 + (size_t)e * 65536;
#pragma unroll
    for (int p = 0; p < 4; ++p) {
      int r = p * 16 + (tid >> 4), d4 = (tid & 15) * 4;
      float4 v = *(const float4*)(src + (size_t)(c0 + r) * 256 + h0 + d4);
      T[r][d4] = v.x; T[r][d4 + 1] = v.y; T[r][d4 + 2] = v.z; T[r][d4 + 3] = v.w;
    }
    __syncthreads();
#pragma unroll
    for (int p = 0; p < 4; ++p) {
      int hr = p * 16 + (tid >> 4), c4 = (tid & 15) * 4;
      USH w[4];
#pragma unroll
      for (int j = 0; j < 4; ++j) w[j] = f2bf(T[c4 + j][hr]);   // W1[e][c0+c4+j][h0+hr]
      int h = h0 + hr;
      int t = h >> 4, lh = h & 15;
      int kt = c0 >> 6, ch = (c4 >> 5) & 1, q = (c4 >> 3) & 3, u0 = c4 & 7;
      size_t idx = ((size_t)((e * 64 + kt * 16 + t) * 2 + ch)) * 512 + (q * 16 + lh) * 8 + u0;
      *(uint2*)(w1f + idx) = *(const uint2*)w;
    }
  } else if (b < 256) {         // w2f
    int bp = b - 128;
    int e = bp >> 4, tl = bp & 15;
    int h0 = (tl >> 2) * 64, d0 = (tl & 3) * 64;
    const float* src = W2 + (size_t)e * 65536;
#pragma unroll
    for (int p = 0; p < 4; ++p) {
      int r = p * 16 + (tid >> 4), d4 = (tid & 15) * 4;
      float4 v = *(const float4*)(src + (size_t)(h0 + r) * 256 + d0 + d4);
      T[r][d4] = v.x; T[r][d4 + 1] = v.y; T[r][d4 + 2] = v.z; T[r][d4 + 3] = v.w;
    }
    __syncthreads();
#pragma unroll
    for (int p = 0; p < 4; ++p) {
      int dr = p * 16 + (tid >> 4), h4 = (tid & 15) * 4;
      USH w[4];
#pragma unroll
      for (int j = 0; j < 4; ++j) w[j] = f2bf(T[h4 + j][dr]);   // W2[e][h0+h4+j][d0+dr]
      int d = d0 + dr;
      int t = d >> 4, ld = d & 15;
      int ht = h0 >> 6, ch = (h4 >> 5) & 1, q = (h4 >> 3) & 3, u0 = h4 & 7;
      size_t idx = ((size_t)((e * 64 + ht * 16 + t) * 2 + ch)) * 512 + (q * 16 + ld) * 8 + u0;
      *(uint2*)(w2f + idx) = *(const uint2*)w;
    }
  } else {                      // wg1f (8 blocks)
    int bp = b - 256;
    int c0 = (bp >> 1) * 64, h0 = (bp & 1) * 64;
#pragma unroll
    for (int p = 0; p < 4; ++p) {
      int r = p * 16 + (tid >> 4), d4 = (tid & 15) * 4;
      float4 v = *(const float4*)(Wg1 + (size_t)(c0 + r) * 128 + h0 + d4);
      T[r][d4] = v.x; T[r][d4 + 1] = v.y; T[r][d4 + 2] = v.z; T[r][d4 + 3] = v.w;
    }
    __syncthreads();
#pragma unroll
    for (int p = 0; p < 4; ++p) {
      int hr = p * 16 + (tid >> 4), c4 = (tid & 15) * 4;
      USH w[4];
#pragma unroll
      for (int j = 0; j < 4; ++j) w[j] = f2bf(T[c4 + j][hr]);   // Wg1[c0+c4+j][h0+hr]
      int h = h0 + hr;
      int t = h >> 4, lh = h & 15;
      int kt = c0 >> 6, ch = (c4 >> 5) & 1, q = (c4 >> 3) & 3, u0 = c4 & 7;
      size_t idx = ((size_t)((kt * 8 + t) * 2 + ch)) * 512 + (q * 16 + lh) * 8 + u0;
      *(uint2*)(wg1f + idx) = *(const uint2*)w;
    }
  }
}

// ---------------- fused gate + experts (256 blocks x 64 rows, 512 thr) ------

__global__ __launch_bounds__(512, 2) void k_moe(
    const float* __restrict__ x,
    const USH* __restrict__ w1f,
    const USH* __restrict__ w2f,
    const USH* __restrict__ wg1f,
    const float* __restrict__ wg2,
    const float* __restrict__ bg1,
    const float* __restrict__ bg2,
    const float* __restrict__ b1,
    const float* __restrict__ b2,
    float* __restrict__ out) {
  __shared__ __align__(16) USH xs[4 * 64 * 64];   // 32KB, swizzled x tile
  __shared__ __align__(16) USH Hs[2][64 * 256];   // 64KB dbuf; Hs[0] doubles as hgs
  __shared__ float b1s[2048];
  __shared__ float b2s[2048];
  __shared__ float gse[512];                      // gse[e*64+n]
  __shared__ float wg2t[8 * 132];                 // wg2t[e][k], padded
  __shared__ float lgg[512];
  __shared__ float bg1s[128];
  __shared__ float bg2g[8];

  int tid = threadIdx.x;
  int wave = tid >> 6, lane = tid & 63;
  int quad = lane >> 4, l16 = lane & 15;
  int sw = l16 & 7;
  int rowBase = blockIdx.x * 64;
  float* hgs = (float*)&Hs[0][0];                 // 64x128 f32, slot-swizzled

  // ---- prologue: x f32 -> bf16 -> xs (swizzled); gate/bias constants
#pragma unroll
  for (int it = 0; it < 4; ++it) {
    int i = it * 512 + tid;
    int kt = i >> 9, rem = i & 511;
    int r = rem >> 3, slot = rem & 7;
    int c8 = slot ^ (r & 7);
    const float* sp = x + (size_t)(rowBase + r) * 256 + kt * 64 + c8 * 8;
    float4 a = *(const float4*)sp;
    float4 bq = *(const float4*)(sp + 4);
    USH v[8];
    v[0] = f2bf(a.x);  v[1] = f2bf(a.y);  v[2] = f2bf(a.z);  v[3] = f2bf(a.w);
    v[4] = f2bf(bq.x); v[5] = f2bf(bq.y); v[6] = f2bf(bq.z); v[7] = f2bf(bq.w);
    *(uint4*)(xs + (size_t)i * 8) = *(const uint4*)v;
  }
#pragma unroll
  for (int t = 0; t < 4; ++t) {
    b1s[t * 512 + tid] = b1[t * 512 + tid];
    b2s[t * 512 + tid] = b2[t * 512 + tid];
  }
  for (int t = tid; t < 1024; t += 512) wg2t[(t & 7) * 132 + (t >> 3)] = wg2[t];
  if (tid < 128) bg1s[tid] = bg1[tid];
  if (tid < 8) bg2g[tid] = bg2[tid];

  // first expert's W1 fragments -> registers (in flight during the gate)
  bf16x8 wra[8], wrb[8];
  auto LDWH = [&](bf16x8* dst, const USH* We, int tb) {
#pragma unroll
    for (int k = 0; k < 2; ++k)
#pragma unroll
      for (int c = 0; c < 2; ++c)
#pragma unroll
        for (int i = 0; i < 2; ++i)
          dst[k * 4 + c * 2 + i] = *(const bf16x8*)(
              We + (size_t)(((tb + k) * 16 + wave * 2 + i) * 2 + c) * 512 + lane * 8);
  };
  LDWH(wra, w1f, 0);
  LDWH(wrb, w1f, 2);

  asm volatile("s_waitcnt lgkmcnt(0)" ::: "memory");
  __builtin_amdgcn_s_barrier();

  // ---- gate stage 1: hg^T[h,n] = sum_c Wg1[c,h]*x[n,c]; wave owns 16 h.
  {
    f32x4 hg4[4] = {};
#pragma unroll
    for (int kt = 0; kt < 4; ++kt)
#pragma unroll
      for (int c = 0; c < 2; ++c) {
        int cs = ((c * 4 + quad) ^ sw) * 8;
        bf16x8 av = *(const bf16x8*)(wg1f + (size_t)((kt * 8 + wave) * 2 + c) * 512 + lane * 8);
        bf16x8 bv[4];
#pragma unroll
        for (int j = 0; j < 4; ++j)
          bv[j] = *(const bf16x8*)(xs + kt * 4096 + (j * 16 + l16) * 64 + cs);
#pragma unroll
        for (int j = 0; j < 4; ++j)
          hg4[j] = __builtin_amdgcn_mfma_f32_16x16x32_bf16(av, bv[j], hg4[j], 0, 0, 0);
      }
    // hgs[n][h] = relu(hg + bg1), h-slot XOR-swizzled (slot = (h>>2)^(n&7))
    int hb = wave * 16 + quad * 4;
    int slotbase = wave * 4 + quad;
#pragma unroll
    for (int j = 0; j < 4; ++j) {
      int n = j * 16 + l16;
      int slot = slotbase ^ (n & 7);
      f32x4 v;
#pragma unroll
      for (int r = 0; r < 4; ++r) v[r] = fmaxf(hg4[j][r] + bg1s[hb + r], 0.0f);
      *(f32x4*)(hgs + n * 128 + slot * 4) = v;
    }
  }
  asm volatile("s_waitcnt lgkmcnt(0)" ::: "memory");
  __builtin_amdgcn_s_barrier();

  // ---- gate stage 2: logits[n][e] (f32, same k-order as before)
  {
    int n = tid >> 3, eg = tid & 7;
    float s = bg2g[eg];
#pragma unroll
    for (int k4 = 0; k4 < 32; ++k4) {
      int slot = k4 ^ (n & 7);
      f32x4 hv = *(const f32x4*)(hgs + n * 128 + slot * 4);
      const float* wv = wg2t + eg * 132 + k4 * 4;
      s += hv[0] * wv[0]; s += hv[1] * wv[1]; s += hv[2] * wv[2]; s += hv[3] * wv[3];
    }
    lgg[tid] = s;
  }
  asm volatile("s_waitcnt lgkmcnt(0)" ::: "memory");
  __builtin_amdgcn_s_barrier();

  if (tid < 64) {               // softmax over 8 experts
    float l[8]; float m = -1e30f;
#pragma unroll
    for (int e = 0; e < 8; ++e) { l[e] = lgg[tid * 8 + e]; m = fmaxf(m, l[e]); }
    float s = 0.0f;
#pragma unroll
    for (int e = 0; e < 8; ++e) { l[e] = expf(l[e] - m); s += l[e]; }
    float inv = 1.0f / s;
#pragma unroll
    for (int e = 0; e < 8; ++e) gse[e * 64 + tid] = l[e] * inv;
  }
  asm volatile("s_waitcnt lgkmcnt(0)" ::: "memory");
  __builtin_amdgcn_s_barrier();   // gse visible; hgs (Hs[0]) now dead

  // ---- x fragments kt=0..2 -> 24 bf16x8 regs (96 VGPR), loaded ONCE.
  // Same addresses phase-1 would read -> numerics identical.
  bf16x8 xr[3][2][4];
#pragma unroll
  for (int kt = 0; kt < 3; ++kt)
#pragma unroll
    for (int c = 0; c < 2; ++c)
#pragma unroll
      for (int j = 0; j < 4; ++j)
        xr[kt][c][j] = *(const bf16x8*)(xs + kt * 4096 + (j * 16 + l16) * 64 +
                                        (((c * 4 + quad) ^ sw) * 8));

  // ---- expert loop (R14b schedule; bv source = xr for kt<3) ----
  f32x4 oacc[4][2] = {};

#pragma unroll 1
  for (int e = 0; e < 8; ++e) {
    const USH* W2e = w2f + (size_t)e * 65536;
    const USH* W1n = w1f + (size_t)((e + 1) & 7) * 65536;
    f32x4 hacc[2][4] = {};

    // phase 1: H^T[h,n] = sum_c W1[c,h]*x[n,c]; wave owns h = wave*32..+31.
#pragma unroll
    for (int kt = 0; kt < 2; ++kt)
#pragma unroll
      for (int c = 0; c < 2; ++c) {
#pragma unroll
        for (int i = 0; i < 2; ++i)
#pragma unroll
          for (int j = 0; j < 4; ++j)
            hacc[i][j] = __builtin_amdgcn_mfma_f32_16x16x32_bf16(
                wra[kt * 4 + c * 2 + i], xr[kt][c][j], hacc[i][j], 0, 0, 0);
      }
    LDWH(wra, W2e, 0);            // refill wra with W2(e) ht=0,1
#pragma unroll
    for (int kt = 2; kt < 4; ++kt)
#pragma unroll
      for (int c = 0; c < 2; ++c) {
        int cs = ((c * 4 + quad) ^ sw) * 8;
        bf16x8 bv[4];
#pragma unroll
        for (int j = 0; j < 4; ++j)
          bv[j] = (kt == 2) ? xr[2][c][j]
                            : *(const bf16x8*)(xs + kt * 4096 + (j * 16 + l16) * 64 + cs);
#pragma unroll
        for (int i = 0; i < 2; ++i)
#pragma unroll
          for (int j = 0; j < 4; ++j)
            hacc[i][j] = __builtin_amdgcn_mfma_f32_16x16x32_bf16(
                wrb[(kt - 2) * 4 + c * 2 + i], bv[j], hacc[i][j], 0, 0, 0);
      }
    LDWH(wrb, W2e, 2);            // refill wrb with W2(e) ht=2,3

    // epilogue 1: Hs[e&1][n][h] = bf16(relu(hacc+b1)*g[n,e])
    USH* Hb = &Hs[e & 1][0];
#pragma unroll
    for (int i = 0; i < 2; ++i) {
      int slot = (wave & 1) * 4 + i * 2 + (quad >> 1);   // (h>>3)&7
      int hb = wave * 32 + i * 16 + quad * 4;
#pragma unroll
      for (int j = 0; j < 4; ++j) {
        int n = j * 16 + l16;
        float gg = gse[e * 64 + n];
        USH w4[4];
#pragma unroll
        for (int r = 0; r < 4; ++r)
          w4[r] = f2bf(fmaxf(hacc[i][j][r] + b1s[e * 256 + hb + r], 0.0f) * gg);
        int off = n * 256 + (wave >> 1) * 64 + ((slot ^ (n & 7)) * 8) + (quad & 1) * 4;
        *(uint2*)(Hb + off) = *(const uint2*)w4;
      }
    }

    // single barrier per expert: LDS drain only; weight prefetches stay live.
    asm volatile("s_waitcnt lgkmcnt(0)" ::: "memory");
    __builtin_amdgcn_s_barrier();

    // phase 2: out[n,d] += sum_h Hs[n,h]*W2[h,d]; wave owns d = wave*32..+31.
#pragma unroll
    for (int ht = 0; ht < 2; ++ht)
#pragma unroll
      for (int c = 0; c < 2; ++c) {
        int cs = ((c * 4 + quad) ^ sw) * 8;
        bf16x8 av[4];
#pragma unroll
        for (int i = 0; i < 4; ++i)
          av[i] = *(const bf16x8*)(Hb + (i * 16 + l16) * 256 + ht * 64 + cs);
#pragma unroll
        for (int i = 0; i < 4; ++i)
#pragma unroll
          for (int j = 0; j < 2; ++j)
            oacc[i][j] = __builtin_amdgcn_mfma_f32_16x16x32_bf16(
                av[i], wra[ht * 4 + c * 2 + j], oacc[i][j], 0, 0, 0);
      }
    LDWH(wra, W1n, 0);            // prefetch next expert's W1 kt=0,1
#pragma unroll
    for (int ht = 2; ht < 4; ++ht)
#pragma unroll
      for (int c = 0; c < 2; ++c) {
        int cs = ((c * 4 + quad) ^ sw) * 8;
        bf16x8 av[4];
#pragma unroll
        for (int i = 0; i < 4; ++i)
          av[i] = *(const bf16x8*)(Hb + (i * 16 + l16) * 256 + ht * 64 + cs);
#pragma unroll
        for (int i = 0; i < 4; ++i)
#pragma unroll
          for (int j = 0; j < 2; ++j)
            oacc[i][j] = __builtin_amdgcn_mfma_f32_16x16x32_bf16(
                av[i], wrb[(ht - 2) * 4 + c * 2 + j], oacc[i][j], 0, 0, 0);
      }
    LDWH(wrb, W1n, 2);            // prefetch next expert's W1 kt=2,3 (e=7: dummy)
  }

  // final epilogue: out = oacc + sum_e g[n,e]*b2[e,d]  (exact f32 bias)
#pragma unroll
  for (int i = 0; i < 4; ++i)
#pragma unroll
    for (int r = 0; r < 4; ++r) {
      int n = i * 16 + quad * 4 + r;
      size_t grow = (size_t)(rowBase + n) * 256;
#pragma unroll
      for (int j = 0; j < 2; ++j) {
        int d = wave * 32 + j * 16 + l16;
        float bias = 0.0f;
#pragma unroll
        for (int ee = 0; ee < 8; ++ee) bias += gse[ee * 64 + n] * b2s[ee * 256 + d];
        out[grow + d] = oacc[i][j][r] + bias;
      }
    }
}

// ---------------- launch ----------------

extern "C" void kernel_launch(void* const* d_in, const int* in_sizes, int n_in,
                              void* d_out, int out_size, void* d_ws, size_t ws_size,
                              hipStream_t stream) {
  const float* x   = (const float*)d_in[0];
  const float* Wg1 = (const float*)d_in[1];
  const float* bg1 = (const float*)d_in[2];
  const float* Wg2 = (const float*)d_in[3];
  const float* bg2 = (const float*)d_in[4];
  const float* W1  = (const float*)d_in[5];
  const float* b1  = (const float*)d_in[6];
  const float* W2  = (const float*)d_in[7];
  const float* b2  = (const float*)d_in[8];
  float* out = (float*)d_out;

  char* ws = (char*)d_ws;
  USH* w1f  = (USH*)(ws + 8388608);
  USH* wg1f = (USH*)(ws + 9437184);
  USH* w2f  = (USH*)(ws + 9502720);

  hipLaunchKernelGGL(k_prep, dim3(264), dim3(256), 0, stream,
                     Wg1, W1, W2, w1f, w2f, wg1f);
  hipLaunchKernelGGL(k_moe, dim3(256), dim3(512), 0, stream,
                     x, w1f, w2f, wg1f, Wg2, bg1, bg2, b1, b2, out);
}